// Round 1
// baseline (21331.123 us; speedup 1.0000x reference)
//
#include <hip/hip_runtime.h>
#include <math.h>

#define NB 512
#define NT 128
#define NN 18
#define NDIM 32
#define NHID 64

// ---------------------------------------------------------------------------
// Fast activations (v_exp_f32-based; ~1e-7 rel err, threshold is 2% -> fine)
// ---------------------------------------------------------------------------
__device__ __forceinline__ float fast_sigmoid(float x) {
    return 1.f / (1.f + __expf(-x));
}
__device__ __forceinline__ float fast_tanh(float x) {
    float xc = fminf(fmaxf(x, -15.f), 15.f);
    float e  = __expf(2.f * xc);
    return (e - 1.f) / (e + 1.f);
}

// ---------------------------------------------------------------------------
// Diffusion stage B: feat[n][(1+2s)C + c] = sum_j S[s][n][j] * feat[j][c]
// for c in [c0, C), both supports. c handled in float4 quads.
// Reads rows [c0,C) only, writes rows >= C: no intra-stage race.
// ---------------------------------------------------------------------------
__device__ __forceinline__ void diffuse_B(float (*feat)[640], const float (*S)[NN][NN],
                                          int C, int c0, int tid) {
    const int span4 = (C - c0) >> 2;
    const int per_s = span4 * NN;
    const int total = 2 * per_s;
    for (int idx = tid; idx < total; idx += 256) {
        int s = (idx >= per_s) ? 1 : 0;
        int r = idx - s * per_s;
        int n = r / span4;
        int c = c0 + ((r - n * span4) << 2);
        const float* Srow = S[s][n];
        float ax = 0.f, ay = 0.f, az = 0.f, aw = 0.f;
#pragma unroll
        for (int j = 0; j < NN; ++j) {
            float sv = Srow[j];
            float4 f = *(const float4*)&feat[j][c];
            ax = fmaf(sv, f.x, ax);
            ay = fmaf(sv, f.y, ay);
            az = fmaf(sv, f.z, az);
            aw = fmaf(sv, f.w, aw);
        }
        float4 o4; o4.x = ax; o4.y = ay; o4.z = az; o4.w = aw;
        *(float4*)&feat[n][(1 + 2 * s) * C + c] = o4;
    }
}

// ---------------------------------------------------------------------------
// Diffusion stage C: feat[n][(2+2s)C + c] = 2*sum_j S[s][n][j]*feat[j][(1+2s)C+c]
//                                           - feat[n][c]
// ---------------------------------------------------------------------------
__device__ __forceinline__ void diffuse_C(float (*feat)[640], const float (*S)[NN][NN],
                                          int C, int c0, int tid) {
    const int span4 = (C - c0) >> 2;
    const int per_s = span4 * NN;
    const int total = 2 * per_s;
    for (int idx = tid; idx < total; idx += 256) {
        int s = (idx >= per_s) ? 1 : 0;
        int r = idx - s * per_s;
        int n = r / span4;
        int c = c0 + ((r - n * span4) << 2);
        const float* Srow = S[s][n];
        const int src = (1 + 2 * s) * C;
        float ax = 0.f, ay = 0.f, az = 0.f, aw = 0.f;
#pragma unroll
        for (int j = 0; j < NN; ++j) {
            float sv = Srow[j];
            float4 f = *(const float4*)&feat[j][src + c];
            ax = fmaf(sv, f.x, ax);
            ay = fmaf(sv, f.y, ay);
            az = fmaf(sv, f.z, az);
            aw = fmaf(sv, f.w, aw);
        }
        float4 x0 = *(const float4*)&feat[n][c];
        float4 o4;
        o4.x = 2.f * ax - x0.x;
        o4.y = 2.f * ay - x0.y;
        o4.z = 2.f * az - x0.z;
        o4.w = 2.f * aw - x0.w;
        *(float4*)&feat[n][(2 + 2 * s) * C + c] = o4;
    }
}

// ---------------------------------------------------------------------------
// Stage A: load feat rows [0,C): concat(input, hidden) transposed into LDS.
// ---------------------------------------------------------------------------
template <int C, bool L0>
__device__ __forceinline__ void stage_A(float (*feat)[640], const float* __restrict__ xg,
                                        const float (*hin)[NHID], const float (*h)[NHID],
                                        int tid) {
    constexpr int Q = C >> 2;  // float4 quads per node row
    for (int idx = tid; idx < NN * Q; idx += 256) {
        int n = idx / Q;
        int c = (idx - n * Q) << 2;
        float4 v;
        if (L0) {
            if (c < NDIM) v = *(const float4*)&xg[n * NDIM + c];
            else          v = *(const float4*)&h[n][c - NDIM];
        } else {
            if (c < NHID) v = *(const float4*)&hin[n][c];
            else          v = *(const float4*)&h[n][c - NHID];
        }
        *(float4*)&feat[n][c] = v;
    }
}

// ---------------------------------------------------------------------------
// Gate matmul + fused sigmoid epilogue.
// 256 threads = 128 output cols x 2 node-halves (9 nodes each).
// o <  64 : r-gate -> write feat[n][DIMin+o] = r * h[n][o]  (cand dconv input)
// o >= 64 : u-gate -> write ubuf[n][o-64]
// ---------------------------------------------------------------------------
template <int C>
__device__ __forceinline__ void gate_mm(const float* __restrict__ Wg,
                                        const float* __restrict__ bg,
                                        float (*feat)[640], float (*h)[NHID],
                                        float (*ubuf)[NHID], int tid) {
    constexpr int Kd    = 5 * C;
    constexpr int DIMin = C - NHID;
    const int o     = tid & 127;
    const int nbase = (tid >> 7) * 9;
    float acc[9];
#pragma unroll
    for (int i = 0; i < 9; ++i) acc[i] = 0.f;

    const float* Wp = Wg + o;
    float w0 = Wp[0], w1 = Wp[128], w2 = Wp[256], w3 = Wp[384];
#pragma unroll 1
    for (int k = 0; k < Kd; k += 4) {
        float cw0 = w0, cw1 = w1, cw2 = w2, cw3 = w3;
        if (k + 4 < Kd) {  // prefetch next weight row group
            Wp += 512;
            w0 = Wp[0]; w1 = Wp[128]; w2 = Wp[256]; w3 = Wp[384];
        }
#pragma unroll
        for (int i = 0; i < 9; ++i) {
            float4 f = *(const float4*)&feat[nbase + i][k];
            acc[i] = fmaf(f.x, cw0, acc[i]);
            acc[i] = fmaf(f.y, cw1, acc[i]);
            acc[i] = fmaf(f.z, cw2, acc[i]);
            acc[i] = fmaf(f.w, cw3, acc[i]);
        }
    }
    __syncthreads();  // all feat reads done before r*h rows are overwritten
    const float bias = bg[o];
    if (o < NHID) {
#pragma unroll
        for (int i = 0; i < 9; ++i) {
            int n = nbase + i;
            float rv = fast_sigmoid(acc[i] + bias);
            feat[n][DIMin + o] = rv * h[n][o];
        }
    } else {
        const int oc = o - NHID;
#pragma unroll
        for (int i = 0; i < 9; ++i) {
            int n = nbase + i;
            ubuf[n][oc] = fast_sigmoid(acc[i] + bias);
        }
    }
    __syncthreads();
}

// ---------------------------------------------------------------------------
// Candidate matmul + fused tanh + GRU state update.
// 256 threads = 64 output cols x 4 node-groups (5,5,5,3 nodes).
// ---------------------------------------------------------------------------
__device__ __forceinline__ void cand_mm(const float* __restrict__ Wc,
                                        const float* __restrict__ bc, int Kd,
                                        float (*feat)[640], float (*h)[NHID],
                                        const float (*ubuf)[NHID], int tid) {
    const int o     = tid & 63;
    const int ng    = tid >> 6;
    const int nbase = ng * 5;
    const int cnt   = (ng == 3) ? 3 : 5;
    float acc[5];
#pragma unroll
    for (int i = 0; i < 5; ++i) acc[i] = 0.f;

    const float* Wp = Wc + o;
    float w0 = Wp[0], w1 = Wp[64], w2 = Wp[128], w3 = Wp[192];
#pragma unroll 1
    for (int k = 0; k < Kd; k += 4) {
        float cw0 = w0, cw1 = w1, cw2 = w2, cw3 = w3;
        if (k + 4 < Kd) {
            Wp += 256;
            w0 = Wp[0]; w1 = Wp[64]; w2 = Wp[128]; w3 = Wp[192];
        }
#pragma unroll
        for (int i = 0; i < 5; ++i) {
            if (i < cnt) {
                float4 f = *(const float4*)&feat[nbase + i][k];
                acc[i] = fmaf(f.x, cw0, acc[i]);
                acc[i] = fmaf(f.y, cw1, acc[i]);
                acc[i] = fmaf(f.z, cw2, acc[i]);
                acc[i] = fmaf(f.w, cw3, acc[i]);
            }
        }
    }
    const float bias = bc[o];
#pragma unroll
    for (int i = 0; i < 5; ++i) {
        if (i < cnt) {
            int n = nbase + i;
            float cv = fast_tanh(acc[i] + bias);
            float uv = ubuf[n][o];
            h[n][o] = uv * h[n][o] + (1.f - uv) * cv;  // only owner touches h[n][o]
        }
    }
    __syncthreads();
}

// ---------------------------------------------------------------------------
// Persistent per-batch kernel: whole T=128 recurrence in one block.
// LDS: 2592 + 46080 + 3*4608 = 62496 B -> 2 blocks/CU (8 waves).
// ---------------------------------------------------------------------------
__global__ __launch_bounds__(256, 2) void dcrnn_kernel(
    const float* __restrict__ x,   const float* __restrict__ sup,
    const float* __restrict__ wg0, const float* __restrict__ bg0,
    const float* __restrict__ wc0, const float* __restrict__ bc0,
    const float* __restrict__ wg1, const float* __restrict__ bg1,
    const float* __restrict__ wc1, const float* __restrict__ bc1,
    const float* __restrict__ fcw, const float* __restrict__ fcb,
    float* __restrict__ out) {
    __shared__ float S_lds[2][NN][NN];
    __shared__ __align__(16) float feat[NN][640];   // feat[n][k], k = m*C + c
    __shared__ __align__(16) float h_a[NN][NHID];
    __shared__ __align__(16) float h_b[NN][NHID];
    __shared__ __align__(16) float ubuf[NN][NHID];

    const int tid = threadIdx.x;
    const int b   = blockIdx.x;

    for (int idx = tid; idx < 2 * NN * NN; idx += 256)
        ((float*)S_lds)[idx] = sup[idx];
    for (int idx = tid; idx < NN * NHID; idx += 256) {
        ((float*)h_a)[idx] = 0.f;
        ((float*)h_b)[idx] = 0.f;
    }
    __syncthreads();

    const float* xb = x + (size_t)b * NT * NN * NDIM;

    for (int t = 0; t < NT; ++t) {
        const float* xt = xb + (size_t)t * NN * NDIM;

        // ---- layer 0 (input dim 32, C = 96, Kd = 480) ----
        stage_A<96, true>(feat, xt, nullptr, h_a, tid);
        __syncthreads();
        diffuse_B(feat, S_lds, 96, 0, tid);
        __syncthreads();
        diffuse_C(feat, S_lds, 96, 0, tid);
        __syncthreads();
        gate_mm<96>(wg0, bg0, feat, h_a, ubuf, tid);   // 2 internal barriers
        diffuse_B(feat, S_lds, 96, 32, tid);           // re-diffuse r*h rows
        __syncthreads();
        diffuse_C(feat, S_lds, 96, 32, tid);
        __syncthreads();
        cand_mm(wc0, bc0, 480, feat, h_a, ubuf, tid);  // barrier at end

        // ---- layer 1 (input = new h_a, C = 128, Kd = 640) ----
        stage_A<128, false>(feat, nullptr, h_a, h_b, tid);
        __syncthreads();
        diffuse_B(feat, S_lds, 128, 0, tid);
        __syncthreads();
        diffuse_C(feat, S_lds, 128, 0, tid);
        __syncthreads();
        gate_mm<128>(wg1, bg1, feat, h_b, ubuf, tid);
        diffuse_B(feat, S_lds, 128, 64, tid);
        __syncthreads();
        diffuse_C(feat, S_lds, 128, 64, tid);
        __syncthreads();
        cand_mm(wc1, bc1, 640, feat, h_b, ubuf, tid);
    }

    // ---- output head: logits[n] = fc_b + relu(h_b[n]) . fc_w ; out[b] = max_n ----
    if (tid < NN) {
        float acc = fcb[0];
#pragma unroll 1
        for (int c = 0; c < NHID; ++c)
            acc = fmaf(fmaxf(h_b[tid][c], 0.f), fcw[c], acc);
        ((float*)ubuf)[tid] = acc;
    }
    __syncthreads();
    if (tid == 0) {
        float m = -1e30f;
#pragma unroll
        for (int n = 0; n < NN; ++n) m = fmaxf(m, ((float*)ubuf)[n]);
        out[b] = m;
    }
}

extern "C" void kernel_launch(void* const* d_in, const int* in_sizes, int n_in,
                              void* d_out, int out_size, void* d_ws, size_t ws_size,
                              hipStream_t stream) {
    const float* x   = (const float*)d_in[0];
    const float* sup = (const float*)d_in[1];
    const float* wg0 = (const float*)d_in[2];
    const float* bg0 = (const float*)d_in[3];
    const float* wc0 = (const float*)d_in[4];
    const float* bc0 = (const float*)d_in[5];
    const float* wg1 = (const float*)d_in[6];
    const float* bg1 = (const float*)d_in[7];
    const float* wc1 = (const float*)d_in[8];
    const float* bc1 = (const float*)d_in[9];
    const float* fcw = (const float*)d_in[10];
    const float* fcb = (const float*)d_in[11];
    float* out = (float*)d_out;

    dcrnn_kernel<<<dim3(NB), dim3(256), 0, stream>>>(
        x, sup, wg0, bg0, wc0, bc0, wg1, bg1, wc1, bc1, fcw, fcb, out);
}

// Round 2
// 8477.694 us; speedup vs baseline: 2.5161x; 2.5161x over previous
//
#include <hip/hip_runtime.h>
#include <math.h>

#define NB 512
#define NT 128
#define NN 18
#define NDIM 32
#define NHID 64

typedef _Float16 half_t;
typedef _Float16 __attribute__((ext_vector_type(2))) half2_t;
typedef float __attribute__((ext_vector_type(4))) float4_t;

// v_dot2_f32_f16: 2 MACs per lane per issue, fp32 accumulate.
#if defined(__has_builtin)
#if __has_builtin(__builtin_amdgcn_fdot2)
#define HAVE_FDOT2 1
#endif
#endif

__device__ __forceinline__ float dot2(half2_t a, half2_t b, float c) {
#ifdef HAVE_FDOT2
    return __builtin_amdgcn_fdot2(a, b, c, false);
#else
    return c + (float)a.x * (float)b.x + (float)a.y * (float)b.y;
#endif
}

__device__ __forceinline__ float fast_sigmoid(float x) {
    return 1.f / (1.f + __expf(-x));
}
__device__ __forceinline__ float fast_tanh(float x) {
    float xc = fminf(fmaxf(x, -15.f), 15.f);
    float e  = __expf(2.f * xc);
    return (e - 1.f) / (e + 1.f);
}

// ---------------------------------------------------------------------------
// Diffusion stage B: feat[n][(1+2s)C + c] = sum_j S[s][n][j] * feat[j][c]
// fp16 storage, fp32 accumulate, 8 columns per work item (one b128).
// ---------------------------------------------------------------------------
template <int C, int c0>
__device__ __forceinline__ void diffuse_B(half_t (*feat)[640], const float (*S)[NN][NN],
                                          int tid) {
    constexpr int span8 = (C - c0) >> 3;
    constexpr int per_s = span8 * NN;
    constexpr int total = 2 * per_s;
    for (int idx = tid; idx < total; idx += 512) {
        int s = (idx >= per_s) ? 1 : 0;
        int r = idx - s * per_s;
        int n = r / span8;
        int c = c0 + ((r - n * span8) << 3);
        const float* Srow = S[s][n];
        float a[8] = {0.f, 0.f, 0.f, 0.f, 0.f, 0.f, 0.f, 0.f};
#pragma unroll
        for (int j = 0; j < NN; ++j) {
            float sv = Srow[j];
            union { float4_t v; half_t h[8]; } f;
            f.v = *(const float4_t*)&feat[j][c];
#pragma unroll
            for (int q = 0; q < 8; ++q) a[q] = fmaf(sv, (float)f.h[q], a[q]);
        }
        union { float4_t v; half_t h[8]; } o;
#pragma unroll
        for (int q = 0; q < 8; ++q) o.h[q] = (half_t)a[q];
        *(float4_t*)&feat[n][(1 + 2 * s) * C + c] = o.v;
    }
}

// ---------------------------------------------------------------------------
// Diffusion stage C: feat[n][(2+2s)C+c] = 2*sum_j S[s][n][j]*feat[j][(1+2s)C+c]
//                                         - feat[n][c]
// ---------------------------------------------------------------------------
template <int C, int c0>
__device__ __forceinline__ void diffuse_C(half_t (*feat)[640], const float (*S)[NN][NN],
                                          int tid) {
    constexpr int span8 = (C - c0) >> 3;
    constexpr int per_s = span8 * NN;
    constexpr int total = 2 * per_s;
    for (int idx = tid; idx < total; idx += 512) {
        int s = (idx >= per_s) ? 1 : 0;
        int r = idx - s * per_s;
        int n = r / span8;
        int c = c0 + ((r - n * span8) << 3);
        const float* Srow = S[s][n];
        const int src = (1 + 2 * s) * C;
        float a[8] = {0.f, 0.f, 0.f, 0.f, 0.f, 0.f, 0.f, 0.f};
#pragma unroll
        for (int j = 0; j < NN; ++j) {
            float sv = Srow[j];
            union { float4_t v; half_t h[8]; } f;
            f.v = *(const float4_t*)&feat[j][src + c];
#pragma unroll
            for (int q = 0; q < 8; ++q) a[q] = fmaf(sv, (float)f.h[q], a[q]);
        }
        union { float4_t v; half_t h[8]; } x0;
        x0.v = *(const float4_t*)&feat[n][c];
        union { float4_t v; half_t h[8]; } o;
#pragma unroll
        for (int q = 0; q < 8; ++q) o.h[q] = (half_t)(2.f * a[q] - (float)x0.h[q]);
        *(float4_t*)&feat[n][(2 + 2 * s) * C + c] = o.v;
    }
}

// ---------------------------------------------------------------------------
// Stage A: feat rows [0,C) = concat(input, hidden), fp32 -> fp16.
// ---------------------------------------------------------------------------
template <int C, bool L0>
__device__ __forceinline__ void stage_A(half_t (*feat)[640], const float* __restrict__ xg,
                                        const float (*hin)[NHID], const float (*h)[NHID],
                                        int tid) {
    constexpr int Q = C >> 3;
    for (int idx = tid; idx < NN * Q; idx += 512) {
        int n = idx / Q;
        int c = (idx - n * Q) << 3;
        const float* src;
        if (L0) src = (c < NDIM) ? &xg[n * NDIM + c] : &h[n][c - NDIM];
        else    src = (c < NHID) ? &hin[n][c] : &h[n][c - NHID];
        union { float4_t f; half_t hh[8]; } o;
#pragma unroll
        for (int q = 0; q < 8; ++q) o.hh[q] = (half_t)src[q];
        *(float4_t*)&feat[n][c] = o.f;
    }
}

// ---------------------------------------------------------------------------
// Gate matmul (fdot2) + fused sigmoid epilogue.
// 512 threads = 128 output cols x 4 node-groups (5,5,4,4 nodes).
// Packed weights: Wq[g*128 + o] is 16B = 8 fp16 for k=8g..8g+7, column o.
// ---------------------------------------------------------------------------
template <int C>
__device__ __forceinline__ void gate_mm(const float4_t* __restrict__ Wq,
                                        const float* __restrict__ bg,
                                        half_t (*feat)[640], float (*h)[NHID],
                                        float (*ubuf)[NHID], int tid) {
    constexpr int G     = (5 * C) / 8;
    constexpr int DIMin = C - NHID;
    const int o     = tid & 127;
    const int ng    = tid >> 7;
    const int cnt   = (ng < 2) ? 5 : 4;
    const int nbase = (ng < 2) ? ng * 5 : 10 + (ng - 2) * 4;
    const float bias = bg[o];
    float acc[5] = {0.f, 0.f, 0.f, 0.f, 0.f};
    float4_t wreg = Wq[o];
#pragma unroll 2
    for (int g = 0; g < G; ++g) {
        union { float4_t v; half2_t h[4]; } wu;
        wu.v = wreg;
        if (g + 1 < G) wreg = Wq[(g + 1) * 128 + o];
        const int kb = g << 3;
#pragma unroll
        for (int i = 0; i < 5; ++i) {
            if (i < cnt) {
                union { float4_t v; half2_t h[4]; } fu;
                fu.v = *(const float4_t*)&feat[nbase + i][kb];
                acc[i] = dot2(fu.h[0], wu.h[0], acc[i]);
                acc[i] = dot2(fu.h[1], wu.h[1], acc[i]);
                acc[i] = dot2(fu.h[2], wu.h[2], acc[i]);
                acc[i] = dot2(fu.h[3], wu.h[3], acc[i]);
            }
        }
    }
    __syncthreads();  // all feat reads done before r*h rows are overwritten
    if (o < NHID) {
#pragma unroll
        for (int i = 0; i < 5; ++i) {
            if (i < cnt) {
                int n = nbase + i;
                float rv = fast_sigmoid(acc[i] + bias);
                feat[n][DIMin + o] = (half_t)(rv * h[n][o]);
            }
        }
    } else {
        const int oc = o - NHID;
#pragma unroll
        for (int i = 0; i < 5; ++i) {
            if (i < cnt) ubuf[nbase + i][oc] = fast_sigmoid(acc[i] + bias);
        }
    }
    __syncthreads();
}

// ---------------------------------------------------------------------------
// Candidate matmul (fdot2) + fused tanh + GRU update.
// 512 threads = 64 output cols x 8 node-groups (3,3,2,2,2,2,2,2 nodes).
// ---------------------------------------------------------------------------
__device__ __forceinline__ void cand_mm(const float4_t* __restrict__ Wq,
                                        const float* __restrict__ bc, int G,
                                        half_t (*feat)[640], float (*h)[NHID],
                                        const float (*ubuf)[NHID], int tid) {
    const int o     = tid & 63;
    const int ng    = tid >> 6;
    const int cnt   = (ng < 2) ? 3 : 2;
    const int nbase = (ng < 2) ? ng * 3 : 6 + (ng - 2) * 2;
    const float bias = bc[o];
    float acc[3] = {0.f, 0.f, 0.f};
    float4_t wreg = Wq[o];
#pragma unroll 2
    for (int g = 0; g < G; ++g) {
        union { float4_t v; half2_t h[4]; } wu;
        wu.v = wreg;
        if (g + 1 < G) wreg = Wq[(g + 1) * 64 + o];
        const int kb = g << 3;
#pragma unroll
        for (int i = 0; i < 3; ++i) {
            if (i < cnt) {
                union { float4_t v; half2_t h[4]; } fu;
                fu.v = *(const float4_t*)&feat[nbase + i][kb];
                acc[i] = dot2(fu.h[0], wu.h[0], acc[i]);
                acc[i] = dot2(fu.h[1], wu.h[1], acc[i]);
                acc[i] = dot2(fu.h[2], wu.h[2], acc[i]);
                acc[i] = dot2(fu.h[3], wu.h[3], acc[i]);
            }
        }
    }
#pragma unroll
    for (int i = 0; i < 3; ++i) {
        if (i < cnt) {
            int n = nbase + i;
            float cv = fast_tanh(acc[i] + bias);
            float uv = ubuf[n][o];
            h[n][o] = uv * h[n][o] + (1.f - uv) * cv;
        }
    }
    __syncthreads();
}

// ---------------------------------------------------------------------------
// Weight pre-pack: W[Kd][ncol] fp32 -> fragment order fp16:
// 16B chunk (g,o) holds W[8g..8g+7][o]. One-time cost per launch (~µs).
// ---------------------------------------------------------------------------
__global__ void pack_weights(const float* __restrict__ W, half_t* __restrict__ Wp,
                             int G, int ncol) {
    int idx = blockIdx.x * blockDim.x + threadIdx.x;
    if (idx >= G * ncol) return;
    int g = idx / ncol;
    int o = idx - g * ncol;
    union { float4_t v; half_t h[8]; } u;
#pragma unroll
    for (int r = 0; r < 8; ++r) u.h[r] = (half_t)W[(g * 8 + r) * ncol + o];
    ((float4_t*)Wp)[idx] = u.v;
}

// ---------------------------------------------------------------------------
// Persistent per-batch kernel: 512 blocks x 512 threads (8 waves).
// LDS: 2592 + 23040 + 3*4608 = 39456 B -> 2 blocks/CU, 16 waves/CU.
// ---------------------------------------------------------------------------
__global__ __launch_bounds__(512, 4) void dcrnn_kernel(
    const float* __restrict__ x,    const float* __restrict__ sup,
    const float4_t* __restrict__ wg0, const float* __restrict__ bg0,
    const float4_t* __restrict__ wc0, const float* __restrict__ bc0,
    const float4_t* __restrict__ wg1, const float* __restrict__ bg1,
    const float4_t* __restrict__ wc1, const float* __restrict__ bc1,
    const float* __restrict__ fcw,  const float* __restrict__ fcb,
    float* __restrict__ out) {
    __shared__ float S_lds[2][NN][NN];
    __shared__ __align__(16) half_t feat[NN][640];
    __shared__ __align__(16) float h_a[NN][NHID];
    __shared__ __align__(16) float h_b[NN][NHID];
    __shared__ __align__(16) float ubuf[NN][NHID];

    const int tid = threadIdx.x;
    const int b   = blockIdx.x;

    for (int idx = tid; idx < 2 * NN * NN; idx += 512)
        ((float*)S_lds)[idx] = sup[idx];
    for (int idx = tid; idx < NN * NHID; idx += 512) {
        ((float*)h_a)[idx] = 0.f;
        ((float*)h_b)[idx] = 0.f;
    }
    __syncthreads();

    const float* xb = x + (size_t)b * NT * NN * NDIM;

    for (int t = 0; t < NT; ++t) {
        const float* xt = xb + (size_t)t * NN * NDIM;

        // ---- layer 0 (C = 96, Kd = 480, G = 60) ----
        stage_A<96, true>(feat, xt, nullptr, h_a, tid);
        __syncthreads();
        diffuse_B<96, 0>(feat, S_lds, tid);
        __syncthreads();
        diffuse_C<96, 0>(feat, S_lds, tid);
        __syncthreads();
        gate_mm<96>(wg0, bg0, feat, h_a, ubuf, tid);   // 2 internal barriers
        diffuse_B<96, 32>(feat, S_lds, tid);           // re-diffuse r*h rows
        __syncthreads();
        diffuse_C<96, 32>(feat, S_lds, tid);
        __syncthreads();
        cand_mm(wc0, bc0, 60, feat, h_a, ubuf, tid);   // barrier at end

        // ---- layer 1 (C = 128, Kd = 640, G = 80) ----
        stage_A<128, false>(feat, nullptr, h_a, h_b, tid);
        __syncthreads();
        diffuse_B<128, 0>(feat, S_lds, tid);
        __syncthreads();
        diffuse_C<128, 0>(feat, S_lds, tid);
        __syncthreads();
        gate_mm<128>(wg1, bg1, feat, h_b, ubuf, tid);
        diffuse_B<128, 64>(feat, S_lds, tid);
        __syncthreads();
        diffuse_C<128, 64>(feat, S_lds, tid);
        __syncthreads();
        cand_mm(wc1, bc1, 80, feat, h_b, ubuf, tid);
    }

    // ---- output head ----
    if (tid < NN) {
        float acc = fcb[0];
#pragma unroll 1
        for (int c = 0; c < NHID; ++c)
            acc = fmaf(fmaxf(h_b[tid][c], 0.f), fcw[c], acc);
        ((float*)ubuf)[tid] = acc;
    }
    __syncthreads();
    if (tid == 0) {
        float m = -1e30f;
#pragma unroll
        for (int n = 0; n < NN; ++n) m = fmaxf(m, ((float*)ubuf)[n]);
        out[b] = m;
    }
}

extern "C" void kernel_launch(void* const* d_in, const int* in_sizes, int n_in,
                              void* d_out, int out_size, void* d_ws, size_t ws_size,
                              hipStream_t stream) {
    const float* x   = (const float*)d_in[0];
    const float* sup = (const float*)d_in[1];
    const float* wg0 = (const float*)d_in[2];
    const float* bg0 = (const float*)d_in[3];
    const float* wc0 = (const float*)d_in[4];
    const float* bc0 = (const float*)d_in[5];
    const float* wg1 = (const float*)d_in[6];
    const float* bg1 = (const float*)d_in[7];
    const float* wc1 = (const float*)d_in[8];
    const float* bc1 = (const float*)d_in[9];
    const float* fcw = (const float*)d_in[10];
    const float* fcb = (const float*)d_in[11];
    float* out = (float*)d_out;

    // Packed fp16 weights in workspace (re-packed every call; 430 KB total).
    char* ws = (char*)d_ws;
    half_t* wg0p = (half_t*)(ws + 0);        // 480x128 -> 122880 B
    half_t* wc0p = (half_t*)(ws + 122880);   // 480x64  ->  61440 B
    half_t* wg1p = (half_t*)(ws + 184320);   // 640x128 -> 163840 B
    half_t* wc1p = (half_t*)(ws + 348160);   // 640x64  ->  81920 B

    pack_weights<<<dim3(30), dim3(256), 0, stream>>>(wg0, wg0p, 60, 128);
    pack_weights<<<dim3(15), dim3(256), 0, stream>>>(wc0, wc0p, 60, 64);
    pack_weights<<<dim3(40), dim3(256), 0, stream>>>(wg1, wg1p, 80, 128);
    pack_weights<<<dim3(20), dim3(256), 0, stream>>>(wc1, wc1p, 80, 64);

    dcrnn_kernel<<<dim3(NB), dim3(512), 0, stream>>>(
        x, sup,
        (const float4_t*)wg0p, bg0, (const float4_t*)wc0p, bc0,
        (const float4_t*)wg1p, bg1, (const float4_t*)wc1p, bc1,
        fcw, fcb, out);
}

// Round 3
// 3925.879 us; speedup vs baseline: 5.4335x; 2.1594x over previous
//
#include <hip/hip_runtime.h>
#include <math.h>

#define NB 512
#define NT 128
#define NN 18
#define NDIM 32
#define NHID 64
#define FSTR 648   // feat row stride in halfs: 648*2B=1296B -> +4 banks/row, conflict-free frags

typedef _Float16 half_t;
typedef _Float16 f16x4 __attribute__((ext_vector_type(4)));
typedef _Float16 f16x8 __attribute__((ext_vector_type(8)));
typedef float    f32x4 __attribute__((ext_vector_type(4)));
typedef float    float4_t __attribute__((ext_vector_type(4)));

__device__ __forceinline__ float fast_sigmoid(float x) {
    return 1.f / (1.f + __expf(-x));
}
__device__ __forceinline__ float fast_tanh(float x) {
    float xc = fminf(fmaxf(x, -15.f), 15.f);
    float e  = __expf(2.f * xc);
    return (e - 1.f) / (e + 1.f);
}

// ---------------------------------------------------------------------------
// Diffusion stage B: feat[n][(1+2s)C + c] = sum_j S[s][n][j] * feat[j][c]
// 2 nodes x 4 cols per work item: each b64 read feeds 8 FMAs (halved LDS BW).
// ---------------------------------------------------------------------------
template <int C, int c0>
__device__ __forceinline__ void diffuse_B(half_t (*feat)[FSTR], const float (*S)[NN][NN],
                                          int tid) {
    constexpr int span4 = (C - c0) >> 2;
    constexpr int per_s = span4 * 9;     // 9 node-pairs
    constexpr int total = 2 * per_s;
    for (int idx = tid; idx < total; idx += 512) {
        int s  = (idx >= per_s) ? 1 : 0;
        int r  = idx - s * per_s;
        int np = r / span4;
        int c  = c0 + ((r - np * span4) << 2);
        int n0 = np * 2;
        const float* S0 = S[s][n0];
        const float* S1 = S[s][n0 + 1];
        float a0[4] = {0.f, 0.f, 0.f, 0.f};
        float a1[4] = {0.f, 0.f, 0.f, 0.f};
#pragma unroll
        for (int j = 0; j < NN; ++j) {
            f16x4 f = *(const f16x4*)&feat[j][c];
            float s0 = S0[j], s1 = S1[j];
#pragma unroll
            for (int q = 0; q < 4; ++q) {
                float fv = (float)f[q];
                a0[q] = fmaf(s0, fv, a0[q]);
                a1[q] = fmaf(s1, fv, a1[q]);
            }
        }
        f16x4 o0, o1;
#pragma unroll
        for (int q = 0; q < 4; ++q) { o0[q] = (half_t)a0[q]; o1[q] = (half_t)a1[q]; }
        *(f16x4*)&feat[n0][(1 + 2 * s) * C + c]     = o0;
        *(f16x4*)&feat[n0 + 1][(1 + 2 * s) * C + c] = o1;
    }
}

// ---------------------------------------------------------------------------
// Diffusion stage C: feat[n][(2+2s)C+c] = 2*sum_j S[s][n][j]*feat[j][(1+2s)C+c]
//                                         - feat[n][c]
// ---------------------------------------------------------------------------
template <int C, int c0>
__device__ __forceinline__ void diffuse_C(half_t (*feat)[FSTR], const float (*S)[NN][NN],
                                          int tid) {
    constexpr int span4 = (C - c0) >> 2;
    constexpr int per_s = span4 * 9;
    constexpr int total = 2 * per_s;
    for (int idx = tid; idx < total; idx += 512) {
        int s  = (idx >= per_s) ? 1 : 0;
        int r  = idx - s * per_s;
        int np = r / span4;
        int c  = c0 + ((r - np * span4) << 2);
        int n0 = np * 2;
        const float* S0 = S[s][n0];
        const float* S1 = S[s][n0 + 1];
        const int src = (1 + 2 * s) * C;
        float a0[4] = {0.f, 0.f, 0.f, 0.f};
        float a1[4] = {0.f, 0.f, 0.f, 0.f};
#pragma unroll
        for (int j = 0; j < NN; ++j) {
            f16x4 f = *(const f16x4*)&feat[j][src + c];
            float s0 = S0[j], s1 = S1[j];
#pragma unroll
            for (int q = 0; q < 4; ++q) {
                float fv = (float)f[q];
                a0[q] = fmaf(s0, fv, a0[q]);
                a1[q] = fmaf(s1, fv, a1[q]);
            }
        }
        f16x4 x00 = *(const f16x4*)&feat[n0][c];
        f16x4 x01 = *(const f16x4*)&feat[n0 + 1][c];
        f16x4 o0, o1;
#pragma unroll
        for (int q = 0; q < 4; ++q) {
            o0[q] = (half_t)(2.f * a0[q] - (float)x00[q]);
            o1[q] = (half_t)(2.f * a1[q] - (float)x01[q]);
        }
        *(f16x4*)&feat[n0][(2 + 2 * s) * C + c]     = o0;
        *(f16x4*)&feat[n0 + 1][(2 + 2 * s) * C + c] = o1;
    }
}

// ---------------------------------------------------------------------------
// Stage A: feat rows [0,C) = concat(input, hidden), fp32 -> fp16.
// ---------------------------------------------------------------------------
template <int C, bool L0>
__device__ __forceinline__ void stage_A(half_t (*feat)[FSTR], const float* __restrict__ xg,
                                        const float (*hin)[NHID], const float (*h)[NHID],
                                        int tid) {
    constexpr int Q = C >> 3;
    for (int idx = tid; idx < NN * Q; idx += 512) {
        int n = idx / Q;
        int c = (idx - n * Q) << 3;
        const float* src;
        if (L0) src = (c < NDIM) ? &xg[n * NDIM + c] : &h[n][c - NDIM];
        else    src = (c < NHID) ? &hin[n][c] : &h[n][c - NHID];
        f16x8 o;
#pragma unroll
        for (int q = 0; q < 8; ++q) o[q] = (half_t)src[q];
        *(f16x8*)&feat[n][c] = o;
    }
}

// ---------------------------------------------------------------------------
// Gate matmul on MFMA 16x16x32 f16. Wave w owns N-tile nt=w (cols nt*16..+16),
// both M-tiles (nodes 0..15, 16..31; rows 18..31 are zero).
// A-frag: lane holds feat[mt*16 + (l&15)][kt*32 + (l>>4)*8 + j]  (1 ds_read_b128)
// B-frag: pre-packed, lane holds W[kt*32+(l>>4)*8+j][nt*16+(l&15)] (1KB coalesced)
// D: lane&15 = col, (lane>>4)*4 + r = row.
// Epilogue fused: r-gate -> feat[n][DIMin+o] = sigmoid*h ; u-gate -> ubuf.
// ---------------------------------------------------------------------------
template <int C>
__device__ __forceinline__ void gate_mm(const f16x8* __restrict__ Wf,
                                        const float* __restrict__ bg,
                                        half_t (*feat)[FSTR], float (*h)[NHID],
                                        float (*ubuf)[NHID], int tid) {
    constexpr int KT    = (5 * C) / 32;
    constexpr int DIMin = C - NHID;
    const int lane = tid & 63;
    const int nt   = tid >> 6;      // 0..7
    const int ln   = lane & 15;
    const int q    = lane >> 4;
    f32x4 acc0 = {0.f, 0.f, 0.f, 0.f};
    f32x4 acc1 = {0.f, 0.f, 0.f, 0.f};
    f16x8 b0 = Wf[(0 * 8 + nt) * 64 + lane];
    f16x8 b1 = Wf[(1 * 8 + nt) * 64 + lane];
#pragma unroll 1
    for (int kt = 0; kt < KT; ++kt) {
        const int kb = kt * 32 + q * 8;
        f16x8 a0 = *(const f16x8*)&feat[ln][kb];
        f16x8 a1 = *(const f16x8*)&feat[16 + ln][kb];
        f16x8 bc = b0;
        b0 = b1;
        if (kt + 2 < KT) b1 = Wf[((kt + 2) * 8 + nt) * 64 + lane];
        acc0 = __builtin_amdgcn_mfma_f32_16x16x32_f16(a0, bc, acc0, 0, 0, 0);
        acc1 = __builtin_amdgcn_mfma_f32_16x16x32_f16(a1, bc, acc1, 0, 0, 0);
    }
    __syncthreads();  // all waves' A-reads done before r*h cols are overwritten
    const int o = nt * 16 + ln;
    const float bias = bg[o];
    if (o < NHID) {
#pragma unroll
        for (int r = 0; r < 4; ++r) {
            int m = q * 4 + r;  // 0..15, all real
            float rv = fast_sigmoid(acc0[r] + bias);
            feat[m][DIMin + o] = (half_t)(rv * h[m][o]);
        }
        if (q == 0) {
#pragma unroll
            for (int r = 0; r < 2; ++r) {  // rows 16,17
                float rv = fast_sigmoid(acc1[r] + bias);
                feat[16 + r][DIMin + o] = (half_t)(rv * h[16 + r][o]);
            }
        }
    } else {
        const int oc = o - NHID;
#pragma unroll
        for (int r = 0; r < 4; ++r)
            ubuf[q * 4 + r][oc] = fast_sigmoid(acc0[r] + bias);
        if (q == 0) {
#pragma unroll
            for (int r = 0; r < 2; ++r)
                ubuf[16 + r][oc] = fast_sigmoid(acc1[r] + bias);
        }
    }
    __syncthreads();
}

// ---------------------------------------------------------------------------
// Candidate matmul on MFMA + fused tanh + GRU update.
// 8 waves = 8 tiles: mt = w&1, nt = w>>1 (cols nt*16..+16 of 64).
// ---------------------------------------------------------------------------
__device__ __forceinline__ void cand_mm(const f16x8* __restrict__ Wf, int KT,
                                        const float* __restrict__ bcv,
                                        half_t (*feat)[FSTR], float (*h)[NHID],
                                        const float (*ubuf)[NHID], int tid) {
    const int lane = tid & 63;
    const int w    = tid >> 6;
    const int mt   = w & 1;
    const int nt   = w >> 1;        // 0..3
    const int ln   = lane & 15;
    const int q    = lane >> 4;
    f32x4 acc = {0.f, 0.f, 0.f, 0.f};
    f16x8 b0 = Wf[(0 * 4 + nt) * 64 + lane];
    f16x8 b1 = Wf[(1 * 4 + nt) * 64 + lane];
#pragma unroll 1
    for (int kt = 0; kt < KT; ++kt) {
        f16x8 a = *(const f16x8*)&feat[mt * 16 + ln][kt * 32 + q * 8];
        f16x8 bc_ = b0;
        b0 = b1;
        if (kt + 2 < KT) b1 = Wf[((kt + 2) * 4 + nt) * 64 + lane];
        acc = __builtin_amdgcn_mfma_f32_16x16x32_f16(a, bc_, acc, 0, 0, 0);
    }
    const int o = nt * 16 + ln;
    const float bias = bcv[o];
#pragma unroll
    for (int r = 0; r < 4; ++r) {
        int m = mt * 16 + q * 4 + r;
        if (m < NN) {
            float cv = fast_tanh(acc[r] + bias);
            float uv = ubuf[m][o];
            h[m][o] = uv * h[m][o] + (1.f - uv) * cv;
        }
    }
    __syncthreads();
}

// ---------------------------------------------------------------------------
// Weight pre-pack into B-fragment order, fp32 -> fp16.
// Frag (kt, nt): lane l holds W[kt*32 + (l>>4)*8 + j][nt*16 + (l&15)], j=0..7.
// ---------------------------------------------------------------------------
__global__ void pack_frags(const float* __restrict__ W, f16x8* __restrict__ out,
                           int KT, int NTl, int ncol) {
    int idx = blockIdx.x * blockDim.x + threadIdx.x;
    if (idx >= KT * NTl * 64) return;
    int lane = idx & 63;
    int fidx = idx >> 6;
    int kt = fidx / NTl;
    int nt = fidx - kt * NTl;
    int ln = lane & 15, q = lane >> 4;
    f16x8 v;
#pragma unroll
    for (int j = 0; j < 8; ++j)
        v[j] = (half_t)W[(kt * 32 + q * 8 + j) * ncol + nt * 16 + ln];
    out[idx] = v;
}

// ---------------------------------------------------------------------------
// Persistent per-batch kernel: 512 blocks x 512 threads (8 waves).
// LDS: 2592 + 41472 + 3*4608 = 57888 B -> 2 blocks/CU, 16 waves/CU.
// ---------------------------------------------------------------------------
__global__ __launch_bounds__(512, 4) void dcrnn_kernel(
    const float* __restrict__ x,    const float* __restrict__ sup,
    const f16x8* __restrict__ wg0,  const float* __restrict__ bg0,
    const f16x8* __restrict__ wc0,  const float* __restrict__ bc0,
    const f16x8* __restrict__ wg1,  const float* __restrict__ bg1,
    const f16x8* __restrict__ wc1,  const float* __restrict__ bc1,
    const float* __restrict__ fcw,  const float* __restrict__ fcb,
    float* __restrict__ out) {
    __shared__ float S_lds[2][NN][NN];
    __shared__ __align__(16) half_t feat[32][FSTR];   // rows 18..31 stay zero (MFMA pad)
    __shared__ __align__(16) float h_a[NN][NHID];
    __shared__ __align__(16) float h_b[NN][NHID];
    __shared__ __align__(16) float ubuf[NN][NHID];

    const int tid = threadIdx.x;
    const int b   = blockIdx.x;

    for (int idx = tid; idx < 2 * NN * NN; idx += 512)
        ((float*)S_lds)[idx] = sup[idx];
    for (int idx = tid; idx < NN * NHID; idx += 512) {
        ((float*)h_a)[idx] = 0.f;
        ((float*)h_b)[idx] = 0.f;
    }
    // zero the 14 pad rows (18..31), full stride
    for (int idx = tid; idx < 14 * (FSTR >> 3); idx += 512) {
        int rr = idx / (FSTR >> 3);
        int cc = (idx - rr * (FSTR >> 3)) << 3;
        f16x8 z = {0, 0, 0, 0, 0, 0, 0, 0};
        *(f16x8*)&feat[18 + rr][cc] = z;
    }
    __syncthreads();

    const float* xb = x + (size_t)b * NT * NN * NDIM;

    for (int t = 0; t < NT; ++t) {
        const float* xt = xb + (size_t)t * NN * NDIM;

        // ---- layer 0 (C = 96, Kd = 480, KT = 15) ----
        stage_A<96, true>(feat, xt, nullptr, h_a, tid);
        __syncthreads();
        diffuse_B<96, 0>(feat, S_lds, tid);
        __syncthreads();
        diffuse_C<96, 0>(feat, S_lds, tid);
        __syncthreads();
        gate_mm<96>(wg0, bg0, feat, h_a, ubuf, tid);   // 2 internal barriers
        diffuse_B<96, 32>(feat, S_lds, tid);           // re-diffuse r*h cols
        __syncthreads();
        diffuse_C<96, 32>(feat, S_lds, tid);
        __syncthreads();
        cand_mm(wc0, 15, bc0, feat, h_a, ubuf, tid);   // barrier at end

        // ---- layer 1 (C = 128, Kd = 640, KT = 20) ----
        stage_A<128, false>(feat, nullptr, h_a, h_b, tid);
        __syncthreads();
        diffuse_B<128, 0>(feat, S_lds, tid);
        __syncthreads();
        diffuse_C<128, 0>(feat, S_lds, tid);
        __syncthreads();
        gate_mm<128>(wg1, bg1, feat, h_b, ubuf, tid);
        diffuse_B<128, 64>(feat, S_lds, tid);
        __syncthreads();
        diffuse_C<128, 64>(feat, S_lds, tid);
        __syncthreads();
        cand_mm(wc1, 20, bc1, feat, h_b, ubuf, tid);
    }

    // ---- output head ----
    if (tid < NN) {
        float acc = fcb[0];
#pragma unroll 1
        for (int c = 0; c < NHID; ++c)
            acc = fmaf(fmaxf(h_b[tid][c], 0.f), fcw[c], acc);
        ((float*)ubuf)[tid] = acc;
    }
    __syncthreads();
    if (tid == 0) {
        float m = -1e30f;
#pragma unroll
        for (int n = 0; n < NN; ++n) m = fmaxf(m, ((float*)ubuf)[n]);
        out[b] = m;
    }
}

extern "C" void kernel_launch(void* const* d_in, const int* in_sizes, int n_in,
                              void* d_out, int out_size, void* d_ws, size_t ws_size,
                              hipStream_t stream) {
    const float* x   = (const float*)d_in[0];
    const float* sup = (const float*)d_in[1];
    const float* wg0 = (const float*)d_in[2];
    const float* bg0 = (const float*)d_in[3];
    const float* wc0 = (const float*)d_in[4];
    const float* bc0 = (const float*)d_in[5];
    const float* wg1 = (const float*)d_in[6];
    const float* bg1 = (const float*)d_in[7];
    const float* wc1 = (const float*)d_in[8];
    const float* bc1 = (const float*)d_in[9];
    const float* fcw = (const float*)d_in[10];
    const float* fcb = (const float*)d_in[11];
    float* out = (float*)d_out;

    // Packed fp16 B-fragments in workspace (430 KB total).
    char* ws = (char*)d_ws;
    f16x8* wg0p = (f16x8*)(ws + 0);        // KT=15, NT=8 -> 122880 B
    f16x8* wc0p = (f16x8*)(ws + 122880);   // KT=15, NT=4 ->  61440 B
    f16x8* wg1p = (f16x8*)(ws + 184320);   // KT=20, NT=8 -> 163840 B
    f16x8* wc1p = (f16x8*)(ws + 348160);   // KT=20, NT=4 ->  81920 B

    pack_frags<<<dim3(30), dim3(256), 0, stream>>>(wg0, wg0p, 15, 8, 128);
    pack_frags<<<dim3(15), dim3(256), 0, stream>>>(wc0, wc0p, 15, 4, 64);
    pack_frags<<<dim3(40), dim3(256), 0, stream>>>(wg1, wg1p, 20, 8, 128);
    pack_frags<<<dim3(20), dim3(256), 0, stream>>>(wc1, wc1p, 20, 4, 64);

    dcrnn_kernel<<<dim3(NB), dim3(512), 0, stream>>>(
        x, sup, wg0p, bg0, wc0p, bc0, wg1p, bg1, wc1p, bc1, fcw, fcb, out);
}

// Round 5
// 3198.509 us; speedup vs baseline: 6.6691x; 1.2274x over previous
//
#include <hip/hip_runtime.h>
#include <math.h>

#define NB 512
#define NT 128
#define NN 18
#define NDIM 32
#define NHID 64

typedef _Float16 half_t;
typedef _Float16 f16x4 __attribute__((ext_vector_type(4)));
typedef _Float16 f16x8 __attribute__((ext_vector_type(8)));
typedef float    f32x4 __attribute__((ext_vector_type(4)));

__device__ __forceinline__ float fast_sigmoid(float x) {
    return 1.f / (1.f + __expf(-x));
}
__device__ __forceinline__ float fast_tanh(float x) {
    float xc = fminf(fmaxf(x, -15.f), 15.f);
    float e  = __expf(2.f * xc);
    return (e - 1.f) / (e + 1.f);
}
__device__ __forceinline__ f32x4 mfma16(f16x8 a, f16x8 b, f32x4 c) {
    return __builtin_amdgcn_mfma_f32_16x16x32_f16(a, b, c, 0, 0, 0);
}

// ---------------------------------------------------------------------------
// MM1: Y(18 x 5*ncol) = Z(18 x C) * W'(C x 5*ncol), all operands frag-order.
//   Z frags in LDS: frag(kt,mt) at (kt*2+mt)*512 halfs, lane-contiguous 16B.
//   W' frags in global: frag(kt,nt') at (kt*NTW+nt')*64 f16x8 (1KB coalesced).
//   Y written to LDS in B-frag order for MM2: row k = 24*m + node_row.
// SCATTER RULE (round-4 race fix): mt=0 writes rows 0..15 (all quads);
// mt=1 writes ONLY quad==0 (rows 16..19; 18,19 are genuine zeros). Rows
// 20..23 of each block and 120..127 stay zero from the one-time init —
// quads 2,3 of mt=1 would alias rows 0..7 of block m+1 (the round-4 bug).
// ---------------------------------------------------------------------------
template <int KT>
__device__ __forceinline__ void mm1(const f16x8* __restrict__ Wf, int NTW, int ncs,
                                    const half_t* Zf, half_t* Yf,
                                    int nt0, int cnt, int lane) {
    f16x8 A[2 * KT];
#pragma unroll
    for (int kt = 0; kt < KT; ++kt) {
        A[kt * 2 + 0] = *(const f16x8*)(Zf + (kt * 2 + 0) * 512 + lane * 8);
        A[kt * 2 + 1] = *(const f16x8*)(Zf + (kt * 2 + 1) * 512 + lane * 8);
    }
    f16x8 B0[KT], B1[KT];
#pragma unroll
    for (int kt = 0; kt < KT; ++kt) B0[kt] = Wf[(kt * NTW + nt0) * 64 + lane];
    if (cnt > 1) {
#pragma unroll
        for (int kt = 0; kt < KT; ++kt) B1[kt] = Wf[(kt * NTW + nt0 + 1) * 64 + lane];
    }
    const int quad = lane >> 4, ln = lane & 15;
#pragma unroll 1
    for (int i = 0; i < cnt; ++i) {
        const int ntp = nt0 + i;
        f16x8 Bc[KT];
#pragma unroll
        for (int kt = 0; kt < KT; ++kt) { Bc[kt] = B0[kt]; B0[kt] = B1[kt]; }
        if (i + 2 < cnt) {
#pragma unroll
            for (int kt = 0; kt < KT; ++kt) B1[kt] = Wf[(kt * NTW + ntp + 2) * 64 + lane];
        }
        f32x4 ac0 = {0.f, 0.f, 0.f, 0.f};
        f32x4 ac1 = {0.f, 0.f, 0.f, 0.f};
#pragma unroll
        for (int kt = 0; kt < KT; ++kt) {
            ac0 = mfma16(A[kt * 2 + 0], Bc[kt], ac0);
            ac1 = mfma16(A[kt * 2 + 1], Bc[kt], ac1);
        }
        const int m  = ntp >> ncs;            // ncol16 = 1<<ncs
        const int ot = ntp - (m << ncs);
        // mt=0: rows k = 24m + quad*4 + r (0..15)
        {
            const int k0 = 24 * m + quad * 4;
            f16x4 pk;
#pragma unroll
            for (int r = 0; r < 4; ++r) pk[r] = (half_t)ac0[r];
            *(f16x4*)(Yf + ((k0 >> 5) * 8 + ot) * 512 +
                      (((((k0 >> 3) & 3) << 4) | ln) * 8) + (k0 & 7)) = pk;
        }
        // mt=1: only quad 0 -> rows 16..19 (16,17 real; 18,19 zero)
        if (quad == 0) {
            const int k0 = 24 * m + 16;       // 24m+16 is a multiple of 8
            f16x4 pk;
#pragma unroll
            for (int r = 0; r < 4; ++r) pk[r] = (half_t)ac1[r];
            *(f16x4*)(Yf + ((k0 >> 5) * 8 + ot) * 512 +
                      (((((k0 >> 3) & 3) << 4) | ln) * 8) + (k0 & 7)) = pk;
        }
    }
}

// ---------------------------------------------------------------------------
// MM2 gate: ru(18 x 128) = Pcat(18 x 120pad128) * Ycat + bias -> sigmoid.
// Wave w = nt2 (0..7) covers both M-tiles. o<64: r -> write r*h into Z frags
// (h-columns, kZ = DIMin+o); o>=64: u -> ubuf. Does NOT read Zf (safe to write).
// ---------------------------------------------------------------------------
__device__ __forceinline__ void mm2_gate(const half_t* Pc, const half_t* Yf,
                                         half_t* Zf, const float* __restrict__ bg,
                                         const float (*h)[NHID], float (*ub)[NHID],
                                         int DIMin, int wv, int lane) {
    const int nt2 = wv, quad = lane >> 4, ln = lane & 15;
    f32x4 a0 = {0.f, 0.f, 0.f, 0.f};
    f32x4 a1 = {0.f, 0.f, 0.f, 0.f};
#pragma unroll
    for (int kt = 0; kt < 4; ++kt) {
        f16x8 B  = *(const f16x8*)(Yf + (kt * 8 + nt2) * 512 + lane * 8);
        f16x8 A0 = *(const f16x8*)(Pc + (kt * 2 + 0) * 512 + lane * 8);
        f16x8 A1 = *(const f16x8*)(Pc + (kt * 2 + 1) * 512 + lane * 8);
        a0 = mfma16(A0, B, a0);
        a1 = mfma16(A1, B, a1);
    }
    const int o = nt2 * 16 + ln;
    const float bias = bg[o];
    if (o < NHID) {
        const int kZ = DIMin + o;
        const int base = ((kZ >> 5) * 2) * 512 + (((kZ >> 3) & 3) << 4) * 8 + (kZ & 7);
#pragma unroll
        for (int r = 0; r < 4; ++r) {
            int n = quad * 4 + r;
            float rv = fast_sigmoid(a0[r] + bias);
            Zf[base + (n & 15) * 8] = (half_t)(rv * h[n][o]);
        }
        if (quad == 0) {
#pragma unroll
            for (int r = 0; r < 2; ++r) {
                int n = 16 + r;
                float rv = fast_sigmoid(a1[r] + bias);
                Zf[base + 512 + (n & 15) * 8] = (half_t)(rv * h[n][o]);
            }
        }
    } else {
        const int oc = o - NHID;
#pragma unroll
        for (int r = 0; r < 4; ++r) ub[quad * 4 + r][oc] = fast_sigmoid(a0[r] + bias);
        if (quad == 0) {
#pragma unroll
            for (int r = 0; r < 2; ++r) ub[16 + r][oc] = fast_sigmoid(a1[r] + bias);
        }
    }
}

// ---------------------------------------------------------------------------
// MM2 cand: c = tanh(Pcat * Ycat + bias); h = u*h + (1-u)*c.
// Wave w: nt2 = w&3, mtA = w>>2.
// ---------------------------------------------------------------------------
__device__ __forceinline__ void mm2_cand(const half_t* Pc, const half_t* Yf,
                                         const float* __restrict__ bc,
                                         float (*h)[NHID], const float (*ub)[NHID],
                                         int wv, int lane) {
    const int nt2 = wv & 3, mtA = wv >> 2;
    const int quad = lane >> 4, ln = lane & 15;
    f32x4 a = {0.f, 0.f, 0.f, 0.f};
#pragma unroll
    for (int kt = 0; kt < 4; ++kt) {
        f16x8 B = *(const f16x8*)(Yf + (kt * 8 + nt2) * 512 + lane * 8);
        f16x8 A = *(const f16x8*)(Pc + (kt * 2 + mtA) * 512 + lane * 8);
        a = mfma16(A, B, a);
    }
    const int o = nt2 * 16 + ln;
    const float bias = bc[o];
#pragma unroll
    for (int r = 0; r < 4; ++r) {
        int n = mtA * 16 + quad * 4 + r;
        if (n < NN) {
            float cv = fast_tanh(a[r] + bias);
            float uv = ub[n][o];
            h[n][o] = uv * h[n][o] + (1.f - uv) * cv;
        }
    }
}

// ---------------------------------------------------------------------------
// Weight pack: W[(m*C + c)][o] fp32 -> MM1 B-frag order fp16.
// Frag (kt, nt'): lane l holds W'[k=kt*32+(l>>4)*8+jj][o' = nt'*16+(l&15)],
// where W'[c][m*ncol+o] = W[m*C+c][o].
// ---------------------------------------------------------------------------
__global__ void pack_w(const float* __restrict__ W, f16x8* __restrict__ out,
                       int KT, int NTW, int ncol, int C) {
    int idx = blockIdx.x * blockDim.x + threadIdx.x;
    if (idx >= KT * NTW * 64) return;
    int lane = idx & 63, f = idx >> 6;
    int kt = f / NTW, ntp = f - kt * NTW;
    int ncol16 = ncol >> 4;
    int m = ntp / ncol16, ot = ntp - m * ncol16;
    int o = ot * 16 + (lane & 15);
    f16x8 v;
#pragma unroll
    for (int jj = 0; jj < 8; ++jj) {
        int c = kt * 32 + ((lane >> 4) << 3) + jj;
        v[jj] = (half_t)W[(m * C + c) * ncol + o];
    }
    out[idx] = v;
}

// ---------------------------------------------------------------------------
// Pcat pack: A-frag order fp16 for MM2. Pcat[n][k=24m+j] = P_m[n][j],
// P0=I, P1=S1, P2=2*S1^2-I, P3=S2, P4=2*S2^2-I; zeros in pad.
// ---------------------------------------------------------------------------
__global__ void pack_pcat(const float* __restrict__ sup, f16x8* __restrict__ out) {
    int tid = threadIdx.x;                 // 512 threads, 1 block
    int lane = tid & 63, fidx = tid >> 6;  // 8 frags: (kt2, mtA)
    int mtA = fidx & 1, kt2 = fidx >> 1;
    int n = mtA * 16 + (lane & 15);
    f16x8 v;
#pragma unroll 1
    for (int jj = 0; jj < 8; ++jj) {
        int k = kt2 * 32 + ((lane >> 4) << 3) + jj;
        int m = k / 24, j = k - m * 24;
        float val = 0.f;
        if (n < NN && j < NN && m < 5) {
            if (m == 0)      val = (n == j) ? 1.f : 0.f;
            else if (m == 1) val = sup[0 * 324 + n * 18 + j];
            else if (m == 3) val = sup[1 * 324 + n * 18 + j];
            else {
                const float* S = sup + ((m == 2) ? 0 : 1) * 324;
                float acc = 0.f;
                for (int l = 0; l < NN; ++l) acc += S[n * 18 + l] * S[l * 18 + j];
                val = 2.f * acc - ((n == j) ? 1.f : 0.f);
            }
        }
        v[jj] = (half_t)val;
    }
    out[fidx * 64 + lane] = v;
}

// ---------------------------------------------------------------------------
// Persistent per-batch kernel: 512 blocks x 512 threads (8 waves).
// LDS: Zf 8K + Yf 32K + Pc 8K + h_a/h_b/ubuf 13.8K = 62.8K -> 2 blocks/CU.
// ---------------------------------------------------------------------------
__global__ __launch_bounds__(512, 4) void dcrnn_kernel(
    const float* __restrict__ x,
    const f16x8* __restrict__ wg0, const float* __restrict__ bg0,
    const f16x8* __restrict__ wc0, const float* __restrict__ bc0,
    const f16x8* __restrict__ wg1, const float* __restrict__ bg1,
    const f16x8* __restrict__ wc1, const float* __restrict__ bc1,
    const f16x8* __restrict__ Pf,
    const float* __restrict__ fcw, const float* __restrict__ fcb,
    float* __restrict__ out) {
    __shared__ __align__(16) half_t Zf[8 * 512];    // Z as A-frags (kt*2+mt)
    __shared__ __align__(16) half_t Yf[32 * 512];   // Ycat as B-frags (kt2*8+ot)
    __shared__ __align__(16) half_t Pc[8 * 512];    // Pcat as A-frags
    __shared__ float h_a[NN][NHID];
    __shared__ float h_b[NN][NHID];
    __shared__ float ubuf[NN][NHID];

    const int tid  = threadIdx.x;
    const int lane = tid & 63;
    const int wv   = tid >> 6;
    const int b    = blockIdx.x;

    // one-time init: zero Z/Y frag pads (pad stays zero forever), load Pcat, zero h
    {
        f16x8 z = {0, 0, 0, 0, 0, 0, 0, 0};
        ((f16x8*)Zf)[tid] = z;
#pragma unroll
        for (int i = 0; i < 4; ++i) ((f16x8*)Yf)[tid + i * 512] = z;
        ((f16x8*)Pc)[tid] = Pf[tid];
        for (int i = tid; i < NN * NHID; i += 512) {
            ((float*)h_a)[i] = 0.f;
            ((float*)h_b)[i] = 0.f;
        }
    }
    __syncthreads();

    const float* xb = x + (size_t)b * NT * NN * NDIM;
    // mm1 wave partitions: gate NTW=40 -> 5/wave; cand NTW=20 -> 3,3,3,3,2,2,2,2
    const int gnt0 = wv * 5;
    const int cnt0 = (wv < 4) ? wv * 3 : 12 + (wv - 4) * 2;
    const int ccnt = (wv < 4) ? 3 : 2;

    for (int t = 0; t < NT; ++t) {
        const float* xt = xb + (size_t)t * NN * NDIM;

        // ======== layer 0: C=96 (KT=3), DIMin=32 ========
        // stage A: Zf <- [x | h_a]
        for (int idx = tid; idx < NN * 12; idx += 512) {
            int n = idx / 12, c8 = idx - n * 12;
            int c = c8 * 8;
            const float* src = (c < NDIM) ? &xt[n * NDIM + c] : &h_a[n][c - NDIM];
            f16x8 o8;
#pragma unroll
            for (int q = 0; q < 8; ++q) o8[q] = (half_t)src[q];
            *(f16x8*)(Zf + ((c8 >> 2) * 2 + (n >> 4)) * 512 +
                      (((c8 & 3) << 4) | (n & 15)) * 8) = o8;
        }
        __syncthreads();
        mm1<3>(wg0, 40, 3, Zf, Yf, gnt0, 5, lane);
        __syncthreads();
        mm2_gate(Pc, Yf, Zf, bg0, h_a, ubuf, 32, wv, lane);
        __syncthreads();
        mm1<3>(wc0, 20, 2, Zf, Yf, cnt0, ccnt, lane);
        __syncthreads();
        mm2_cand(Pc, Yf, bc0, h_a, ubuf, wv, lane);
        __syncthreads();

        // ======== layer 1: C=128 (KT=4), DIMin=64 ========
        for (int idx = tid; idx < NN * 16; idx += 512) {
            int n = idx >> 4, c8 = idx & 15;
            int c = c8 * 8;
            const float* src = (c < NHID) ? &h_a[n][c] : &h_b[n][c - NHID];
            f16x8 o8;
#pragma unroll
            for (int q = 0; q < 8; ++q) o8[q] = (half_t)src[q];
            *(f16x8*)(Zf + ((c8 >> 2) * 2 + (n >> 4)) * 512 +
                      (((c8 & 3) << 4) | (n & 15)) * 8) = o8;
        }
        __syncthreads();
        mm1<4>(wg1, 40, 3, Zf, Yf, gnt0, 5, lane);
        __syncthreads();
        mm2_gate(Pc, Yf, Zf, bg1, h_b, ubuf, 64, wv, lane);
        __syncthreads();
        mm1<4>(wc1, 20, 2, Zf, Yf, cnt0, ccnt, lane);
        __syncthreads();
        mm2_cand(Pc, Yf, bc1, h_b, ubuf, wv, lane);
        __syncthreads();
    }

    // ---- output head: out[b] = max_n (relu(h_b[n]) . fcw + fcb) ----
    if (tid < NN) {
        float acc = fcb[0];
#pragma unroll 1
        for (int c = 0; c < NHID; ++c)
            acc = fmaf(fmaxf(h_b[tid][c], 0.f), fcw[c], acc);
        ((float*)ubuf)[tid] = acc;
    }
    __syncthreads();
    if (tid == 0) {
        float m = -1e30f;
#pragma unroll
        for (int n = 0; n < NN; ++n) m = fmaxf(m, ((float*)ubuf)[n]);
        out[b] = m;
    }
}

extern "C" void kernel_launch(void* const* d_in, const int* in_sizes, int n_in,
                              void* d_out, int out_size, void* d_ws, size_t ws_size,
                              hipStream_t stream) {
    const float* x   = (const float*)d_in[0];
    const float* sup = (const float*)d_in[1];
    const float* wg0 = (const float*)d_in[2];
    const float* bg0 = (const float*)d_in[3];
    const float* wc0 = (const float*)d_in[4];
    const float* bc0 = (const float*)d_in[5];
    const float* wg1 = (const float*)d_in[6];
    const float* bg1 = (const float*)d_in[7];
    const float* wc1 = (const float*)d_in[8];
    const float* bc1 = (const float*)d_in[9];
    const float* fcw = (const float*)d_in[10];
    const float* fcb = (const float*)d_in[11];
    float* out = (float*)d_out;

    // ws: packed fp16 MM1 B-frags + Pcat A-frags (438272 B total)
    char* ws = (char*)d_ws;
    f16x8* wg0p = (f16x8*)(ws + 0);        // KT=3, NTW=40 -> 122880 B
    f16x8* wc0p = (f16x8*)(ws + 122880);   // KT=3, NTW=20 ->  61440 B
    f16x8* wg1p = (f16x8*)(ws + 184320);   // KT=4, NTW=40 -> 163840 B
    f16x8* wc1p = (f16x8*)(ws + 348160);   // KT=4, NTW=20 ->  81920 B
    f16x8* pfp  = (f16x8*)(ws + 430080);   // 8 frags      ->   8192 B

    pack_w<<<dim3(30), dim3(256), 0, stream>>>(wg0, wg0p, 3, 40, 128, 96);
    pack_w<<<dim3(15), dim3(256), 0, stream>>>(wc0, wc0p, 3, 20, 64, 96);
    pack_w<<<dim3(40), dim3(256), 0, stream>>>(wg1, wg1p, 4, 40, 128, 128);
    pack_w<<<dim3(20), dim3(256), 0, stream>>>(wc1, wc1p, 4, 20, 64, 128);
    pack_pcat<<<dim3(1), dim3(512), 0, stream>>>(sup, pfp);

    dcrnn_kernel<<<dim3(NB), dim3(512), 0, stream>>>(
        x, wg0p, bg0, wc0p, bc0, wg1p, bg1, wc1p, bc1, pfp, fcw, fcb, out);
}